// Round 5
// baseline (252.033 us; speedup 1.0000x reference)
//
#include <hip/hip_runtime.h>

typedef __attribute__((ext_vector_type(4))) float f32x4;
typedef __attribute__((ext_vector_type(8))) short s16x8;

#define NTOK 65536
#define KEXT 1056  // 8 pairs of [64 Wb-k | 64 We-k] = 1024, tail 32

__device__ __forceinline__ unsigned short f2b(float f) {
    unsigned int u = __float_as_uint(f);
    u = (u + 0x7FFFu + ((u >> 16) & 1u)) >> 16;
    return (unsigned short)u;
}

__device__ __forceinline__ void gld_lds16(const void* g, void* l) {
    __builtin_amdgcn_global_load_lds(
        (const __attribute__((address_space(1))) unsigned int*)g,
        (__attribute__((address_space(3))) unsigned int*)l, 16, 0, 0);
}

// ---------------- P1: build Wcat[e][512 cols][KEXT] bf16 (K interleaved) ----
// k<1024: pair p=k>>7, q=k&127: q<64 -> ia3*Wb col p*64+q ; q>=64 -> We col
// p*64+(q-64). Tail: 1024..1031 = 4*ia3*B rows, 1032 = ia3*bb, 1033 = be, 0.
__global__ __launch_bounds__(256) void prep_kernel(
    const float* __restrict__ Wb, const float* __restrict__ bb,
    const float* __restrict__ B, const float* __restrict__ ia3,
    const float* __restrict__ We, const float* __restrict__ be,
    unsigned short* __restrict__ Wcat, int* __restrict__ cnt)
{
    int i = blockIdx.x * 256 + threadIdx.x;
    if (i < 4) cnt[i] = 0;
    if (i >= 4 * 512 * KEXT) return;
    const int k = i % KEXT;
    const int r = (i / KEXT) & 511;
    const int e = i / (KEXT * 512);
    float v;
    if (k < 1024) {
        const int p = k >> 7, q = k & 127;
        if (q < 64) v = Wb[r * 512 + p * 64 + q] * ia3[r];
        else        v = We[((size_t)e * 512 + r) * 512 + p * 64 + (q - 64)];
    }
    else if (k < 1032)  v = B[(k - 1024) * 512 + r] * 4.0f * ia3[r];
    else if (k == 1032) v = bb[r] * ia3[r];
    else if (k == 1033) v = be[e * 512 + r];
    else                v = 0.0f;
    Wcat[i] = f2b(v);
}

// ---------------- P2: router + LoRA-t + expert compaction -------------------
__global__ __launch_bounds__(256) void router_kernel(
    const float* __restrict__ x, const float* __restrict__ A,
    const float* __restrict__ Wr, const float* __restrict__ br,
    float* __restrict__ wgt, float* __restrict__ tws,
    int* __restrict__ perm, int* __restrict__ cnt)
{
    __shared__ int sCnt[4];
    __shared__ int sBase[4];
    __shared__ int sE[64];
    __shared__ int sPos[64];

    const int tid = threadIdx.x;
    const int wave = tid >> 6, lane = tid & 63;
    const int k0 = lane * 8;

    f32x4 wrv[4][2];
#pragma unroll
    for (int e = 0; e < 4; ++e) {
        wrv[e][0] = *(const f32x4*)(Wr + e * 512 + k0);
        wrv[e][1] = *(const f32x4*)(Wr + e * 512 + k0 + 4);
    }
    f32x4 av[8][2];
#pragma unroll
    for (int j = 0; j < 8; ++j) {
        av[j][0] = *(const f32x4*)(A + (size_t)(k0 + j) * 8);
        av[j][1] = *(const f32x4*)(A + (size_t)(k0 + j) * 8 + 4);
    }
    const float br0 = br[0], br1 = br[1], br2 = br[2], br3 = br[3];

    if (tid < 4) sCnt[tid] = 0;
    __syncthreads();

    const int tok0 = blockIdx.x * 64 + wave * 16;
    for (int it = 0; it < 16; ++it) {
        const int tok = tok0 + it;
        const float* xr = x + (size_t)tok * 512 + k0;
        f32x4 x0 = *(const f32x4*)xr;
        f32x4 x1 = *(const f32x4*)(xr + 4);
        float ar[4] = {0.f, 0.f, 0.f, 0.f};
        float at[8] = {0.f, 0.f, 0.f, 0.f, 0.f, 0.f, 0.f, 0.f};
#pragma unroll
        for (int j = 0; j < 8; ++j) {
            const float xv = (j < 4) ? x0[j] : x1[j - 4];
#pragma unroll
            for (int e = 0; e < 4; ++e) ar[e] += xv * wrv[e][j >> 2][j & 3];
#pragma unroll
            for (int r = 0; r < 8; ++r) at[r] += xv * av[j][r >> 2][r & 3];
        }
#pragma unroll
        for (int off = 32; off >= 1; off >>= 1) {
#pragma unroll
            for (int e = 0; e < 4; ++e) ar[e] += __shfl_xor(ar[e], off);
#pragma unroll
            for (int r = 0; r < 8; ++r) at[r] += __shfl_xor(at[r], off);
        }
        if (lane == 0) {
            const float l0 = ar[0] + br0, l1 = ar[1] + br1;
            const float l2 = ar[2] + br2, l3 = ar[3] + br3;
            int e = 0; float m = l0;
            if (l1 > m) { m = l1; e = 1; }
            if (l2 > m) { m = l2; e = 2; }
            if (l3 > m) { m = l3; e = 3; }
            const float s = expf(l0 - m) + expf(l1 - m) + expf(l2 - m) + expf(l3 - m);
            wgt[tok] = 1.0f / s;  // top value is exp(0)=1
            float* tp = tws + (size_t)tok * 8;
#pragma unroll
            for (int r = 0; r < 8; ++r) tp[r] = at[r];
            const int slot = wave * 16 + it;
            sE[slot] = e;
            sPos[slot] = atomicAdd(&sCnt[e], 1);
        }
    }
    __syncthreads();
    if (tid < 4) sBase[tid] = atomicAdd(&cnt[tid], sCnt[tid]);
    __syncthreads();
    if (tid < 64) {
        const int e = sE[tid];
        perm[e * NTOK + sBase[e] + sPos[tid]] = blockIdx.x * 64 + tid;
    }
}

// ---------------- P3: fused GEMM 128x256xKEXT, 2 blocks/CU ------------------
// 512 thr / 8 waves, BK=32, LDS 48 KB, <=128 unified regs -> 2 resident
// blocks per CU whose barriers interleave (m114 implicit overlap).
// bid&7 -> xcd: e = xcd>>1, tile_m parity = xcd&1 (weights L2-pinned).
__global__ __launch_bounds__(512, 4) void main_kernel(
    const float* __restrict__ x, const unsigned short* __restrict__ Wcat,
    const float* __restrict__ wgt, const float* __restrict__ tws,
    const int* __restrict__ perm, const int* __restrict__ cnt,
    float* __restrict__ out)
{
    __shared__ unsigned short sA[2][128 * 32];   // 2 x 8 KB
    __shared__ unsigned short sB[2][256 * 32];   // 2 x 16 KB

    const int bid = blockIdx.x;
    const int xcd = bid & 7;
    const int e = xcd >> 1;
    const int tl = bid >> 3;
    const int half = tl & 1;
    const int tile_m = ((tl >> 1) << 1) + (xcd & 1);
    const int n = cnt[e];
    const int base = tile_m * 128;
    if (base >= n) return;
    const int mcount = min(128, n - base);

    const int tid = threadIdx.x;
    const int lane = tid & 63;
    const int wave = tid >> 6;        // 0..7
    const int lanelo = lane & 15;
    const int g = lane >> 4;          // 0..3
    const int mw = wave >> 2;         // 0..1  (64-row block)
    const int nw = wave & 3;          // 0..3  (64-col block)

    // ---- A staging map: thread -> (arow 0..127, aseg 0..3 of 8 f32) ----
    const int arow = tid >> 2;
    const int aseg = tid & 3;
    const int atok = perm[e * NTOK + base + min(arow, mcount - 1)];
    const float* axp = x + (size_t)atok * 512;
    const float* atp = tws + (size_t)atok * 8;
    const float aw = wgt[atok];
    const int adst = arow * 64 + ((aseg ^ (arow & 3)) << 4);   // bytes

    // ---- B staging: 2 gld groups/wave, pre-swizzled source, linear dest ----
    const unsigned short* wcE = Wcat + ((size_t)e * 512 + half * 256) * KEXT;
    const unsigned short* bsrc[2];
    int bdst[2];
#pragma unroll
    for (int i = 0; i < 2; ++i) {
        const int wp = wave * 2 + i;              // 0..15 (16-row groups)
        const int wr = wp * 16 + (lane >> 2);     // 0..255 weight row
        bsrc[i] = wcE + (size_t)wr * KEXT + (((lane & 3) ^ (wr & 3)) << 3);
        bdst[i] = wp * 1024;                      // bytes
    }

    // two named staging pairs (rule #20: static names, no runtime index)
    f32x4 pa0, pa1, pb0, pb1;
    auto loadA = [&](int ch) {
        if (ch < 32) {
            const int sub = ch & 3;
            if (sub < 2) {
                const float* s = axp + (ch >> 2) * 64 + sub * 32 + aseg * 8;
                if (sub == 0) { pa0 = *(const f32x4*)s; pa1 = *(const f32x4*)(s + 4); }
                else          { pb0 = *(const f32x4*)s; pb1 = *(const f32x4*)(s + 4); }
            }
        } else {
            pa0 = *(const f32x4*)atp; pa1 = *(const f32x4*)(atp + 4);
        }
    };
    auto writeA = [&](int ch, int buf) {
        s16x8 hv;
        if (ch < 32) {
            const int sub = ch & 3;
            const f32x4 q0 = (sub & 1) ? pb0 : pa0;
            const f32x4 q1 = (sub & 1) ? pb1 : pa1;
            const float s = (sub & 2) ? aw : 1.0f;
#pragma unroll
            for (int j = 0; j < 4; ++j) { hv[j] = (short)f2b(s * q0[j]); hv[j + 4] = (short)f2b(s * q1[j]); }
        } else {
#pragma unroll
            for (int j = 0; j < 8; ++j) hv[j] = 0;
            if (aseg == 0) {
#pragma unroll
                for (int j = 0; j < 4; ++j) { hv[j] = (short)f2b(pa0[j]); hv[j + 4] = (short)f2b(pa1[j]); }
            } else if (aseg == 1) {
                hv[0] = (short)f2b(1.0f);
                hv[1] = (short)f2b(aw);
            }
        }
        *(s16x8*)((char*)sA[buf] + adst) = hv;
    };
    auto issueB = [&](int ch, int buf) {
#pragma unroll
        for (int i = 0; i < 2; ++i)
            gld_lds16(bsrc[i] + ch * 32, (char*)sB[buf] + bdst[i]);
    };

    // ---- prologue: stage chunk 0 ----
    loadA(0);
    issueB(0, 0);
    writeA(0, 0);
    __syncthreads();

    f32x4 acc[4][4];
#pragma unroll
    for (int mb = 0; mb < 4; ++mb)
#pragma unroll
        for (int nb = 0; nb < 4; ++nb) acc[mb][nb] = (f32x4){0.f, 0.f, 0.f, 0.f};

    for (int c = 0; c < 33; ++c) {
        const int cur = c & 1, nxt = cur ^ 1;
        if (c < 32) {
            loadA(c + 1);        // T14: issue globals early
            issueB(c + 1, nxt);  // fire-and-forget into other buffer
        }
        const char* bufA = (const char*)sA[cur];
        const char* bufB = (const char*)sB[cur];
        s16x8 a[4];
#pragma unroll
        for (int mb = 0; mb < 4; ++mb) {
            const int row = mw * 64 + mb * 16 + lanelo;
            a[mb] = *(const s16x8*)(bufA + row * 64 + ((g ^ (row & 3)) << 4));
        }
#pragma unroll
        for (int nb = 0; nb < 4; ++nb) {
            const int wr = nw * 64 + nb * 16 + lanelo;
            const s16x8 b = *(const s16x8*)(bufB + wr * 64 + ((g ^ (wr & 3)) << 4));
            __builtin_amdgcn_s_setprio(1);
#pragma unroll
            for (int mb = 0; mb < 4; ++mb)
                acc[mb][nb] = __builtin_amdgcn_mfma_f32_16x16x32_bf16(a[mb], b, acc[mb][nb], 0, 0, 0);
            __builtin_amdgcn_s_setprio(0);
        }
        if (c < 32) {
            writeA(c + 1, nxt);
            __syncthreads();
        }
    }

    // ---- epilogue: bare scattered store ----
    const int col0 = half * 256 + nw * 64 + lanelo;
#pragma unroll
    for (int mb = 0; mb < 4; ++mb) {
#pragma unroll
        for (int r = 0; r < 4; ++r) {
            const int trow = mw * 64 + mb * 16 + g * 4 + r;
            if (trow < mcount) {
                const int tok = perm[e * NTOK + base + trow];
                float* orow = out + (size_t)tok * 512 + col0;
                orow[0]  = acc[mb][0][r];
                orow[16] = acc[mb][1][r];
                orow[32] = acc[mb][2][r];
                orow[48] = acc[mb][3][r];
            }
        }
    }
}

extern "C" void kernel_launch(void* const* d_in, const int* in_sizes, int n_in,
                              void* d_out, int out_size, void* d_ws, size_t ws_size,
                              hipStream_t stream)
{
    const float* x   = (const float*)d_in[0];
    const float* Wb  = (const float*)d_in[1];
    const float* bb  = (const float*)d_in[2];
    const float* A   = (const float*)d_in[3];
    const float* B   = (const float*)d_in[4];
    const float* ia3 = (const float*)d_in[5];
    const float* Wr  = (const float*)d_in[6];
    const float* br  = (const float*)d_in[7];
    const float* We  = (const float*)d_in[8];
    const float* be  = (const float*)d_in[9];
    float* out = (float*)d_out;

    char* w = (char*)d_ws;
    int* cnt             = (int*)w;                      // 256 B
    unsigned short* Wcat = (unsigned short*)(w + 256);   // 4*512*1056*2 = 4325376
    float* wgt           = (float*)(w + 4325632);        // 65536*4
    float* tws           = (float*)(w + 4587776);        // 65536*8*4
    int* perm            = (int*)(w + 6684928);          // 4*65536*4 -> end 7733504

    hipLaunchKernelGGL(prep_kernel, dim3(8448), dim3(256), 0, stream,
                       Wb, bb, B, ia3, We, be, Wcat, cnt);
    hipLaunchKernelGGL(router_kernel, dim3(1024), dim3(256), 0, stream,
                       x, A, Wr, br, wgt, tws, perm, cnt);
    hipLaunchKernelGGL(main_kernel, dim3(4096), dim3(512), 0, stream,
                       x, Wcat, wgt, tws, perm, cnt, out);
}

// Round 6
// 211.692 us; speedup vs baseline: 1.1906x; 1.1906x over previous
//
#include <hip/hip_runtime.h>

typedef __attribute__((ext_vector_type(4))) float f32x4;
typedef __attribute__((ext_vector_type(8))) short s16x8;

#define NTOK 65536
#define KEXT 1088  // 8 pairs of [64 Wb-k | 64 We-k] = 1024, then tail 64

__device__ __forceinline__ unsigned short f2b(float f) {
    unsigned int u = __float_as_uint(f);
    u = (u + 0x7FFFu + ((u >> 16) & 1u)) >> 16;
    return (unsigned short)u;
}

__device__ __forceinline__ void gld_lds16(const void* g, void* l) {
    __builtin_amdgcn_global_load_lds(
        (const __attribute__((address_space(1))) unsigned int*)g,
        (__attribute__((address_space(3))) unsigned int*)l, 16, 0, 0);
}

// ---------------- P1: build Wcat[e][512 cols][KEXT] bf16 (K interleaved) ----
// K pair p (0..7): k = p*128+q ; q<64 -> ia3*Wb col p*64+q ; q>=64 -> We col
// p*64+(q-64). Tail: 1024..1031 = 4*ia3*B rows, 1032 = ia3*bb, 1033 = be.
__global__ __launch_bounds__(256) void prep_kernel(
    const float* __restrict__ Wb, const float* __restrict__ bb,
    const float* __restrict__ B, const float* __restrict__ ia3,
    const float* __restrict__ We, const float* __restrict__ be,
    unsigned short* __restrict__ Wcat, int* __restrict__ cnt)
{
    int i = blockIdx.x * 256 + threadIdx.x;
    if (i < 4) cnt[i] = 0;
    if (i >= 4 * 512 * KEXT) return;
    const int k = i % KEXT;
    const int r = (i / KEXT) & 511;
    const int e = i / (KEXT * 512);
    float v;
    if (k < 1024) {
        const int p = k >> 7, q = k & 127;
        if (q < 64) v = Wb[r * 512 + p * 64 + q] * ia3[r];
        else        v = We[((size_t)e * 512 + r) * 512 + p * 64 + (q - 64)];
    }
    else if (k < 1032)  v = B[(k - 1024) * 512 + r] * 4.0f * ia3[r];
    else if (k == 1032) v = bb[r] * ia3[r];
    else if (k == 1033) v = be[e * 512 + r];
    else                v = 0.0f;
    Wcat[i] = f2b(v);
}

// ---------------- P2: router + LoRA-t + expert compaction -------------------
__global__ __launch_bounds__(256) void router_kernel(
    const float* __restrict__ x, const float* __restrict__ A,
    const float* __restrict__ Wr, const float* __restrict__ br,
    float* __restrict__ wgt, float* __restrict__ tws,
    int* __restrict__ perm, int* __restrict__ cnt)
{
    __shared__ int sCnt[4];
    __shared__ int sBase[4];
    __shared__ int sE[64];
    __shared__ int sPos[64];

    const int tid = threadIdx.x;
    const int wave = tid >> 6, lane = tid & 63;
    const int k0 = lane * 8;

    f32x4 wrv[4][2];
#pragma unroll
    for (int e = 0; e < 4; ++e) {
        wrv[e][0] = *(const f32x4*)(Wr + e * 512 + k0);
        wrv[e][1] = *(const f32x4*)(Wr + e * 512 + k0 + 4);
    }
    f32x4 av[8][2];
#pragma unroll
    for (int j = 0; j < 8; ++j) {
        av[j][0] = *(const f32x4*)(A + (size_t)(k0 + j) * 8);
        av[j][1] = *(const f32x4*)(A + (size_t)(k0 + j) * 8 + 4);
    }
    const float br0 = br[0], br1 = br[1], br2 = br[2], br3 = br[3];

    if (tid < 4) sCnt[tid] = 0;
    __syncthreads();

    const int tok0 = blockIdx.x * 64 + wave * 16;
    for (int it = 0; it < 16; ++it) {
        const int tok = tok0 + it;
        const float* xr = x + (size_t)tok * 512 + k0;
        f32x4 x0 = *(const f32x4*)xr;
        f32x4 x1 = *(const f32x4*)(xr + 4);
        float ar[4] = {0.f, 0.f, 0.f, 0.f};
        float at[8] = {0.f, 0.f, 0.f, 0.f, 0.f, 0.f, 0.f, 0.f};
#pragma unroll
        for (int j = 0; j < 8; ++j) {
            const float xv = (j < 4) ? x0[j] : x1[j - 4];
#pragma unroll
            for (int e = 0; e < 4; ++e) ar[e] += xv * wrv[e][j >> 2][j & 3];
#pragma unroll
            for (int r = 0; r < 8; ++r) at[r] += xv * av[j][r >> 2][r & 3];
        }
#pragma unroll
        for (int off = 32; off >= 1; off >>= 1) {
#pragma unroll
            for (int e = 0; e < 4; ++e) ar[e] += __shfl_xor(ar[e], off);
#pragma unroll
            for (int r = 0; r < 8; ++r) at[r] += __shfl_xor(at[r], off);
        }
        if (lane == 0) {
            const float l0 = ar[0] + br0, l1 = ar[1] + br1;
            const float l2 = ar[2] + br2, l3 = ar[3] + br3;
            int e = 0; float m = l0;
            if (l1 > m) { m = l1; e = 1; }
            if (l2 > m) { m = l2; e = 2; }
            if (l3 > m) { m = l3; e = 3; }
            const float s = expf(l0 - m) + expf(l1 - m) + expf(l2 - m) + expf(l3 - m);
            wgt[tok] = 1.0f / s;  // top value is exp(0)=1
            float* tp = tws + (size_t)tok * 8;
#pragma unroll
            for (int r = 0; r < 8; ++r) tp[r] = at[r];
            const int slot = wave * 16 + it;
            sE[slot] = e;
            sPos[slot] = atomicAdd(&sCnt[e], 1);
        }
    }
    __syncthreads();
    if (tid < 4) sBase[tid] = atomicAdd(&cnt[tid], sCnt[tid]);
    __syncthreads();
    if (tid < 64) {
        const int e = sE[tid];
        perm[e * NTOK + sBase[e] + sPos[tid]] = blockIdx.x * 64 + tid;
    }
}

// ---------------- P3: fused GEMM 128x512xKEXT, counted-vmcnt pipeline -------
// Round-4 geometry (16 waves, wave-tile 64x64, 160 KB LDS, XCD-pinned) with
// the T3/T4 transformation: per chunk, counted s_waitcnt vmcnt(4|6) retires
// ONLY chunk-c's 4 gld_lds; chunk-(c+1)'s loads stay in flight across both
// barriers. Never vmcnt(0) in the main loop.
__global__ __launch_bounds__(1024) void main_kernel(
    const float* __restrict__ x, const unsigned short* __restrict__ Wcat,
    const float* __restrict__ wgt, const float* __restrict__ tws,
    const int* __restrict__ perm, const int* __restrict__ cnt,
    float* __restrict__ out)
{
    __shared__ unsigned short sA[2][128 * 64];   // 2 x 16 KB
    __shared__ unsigned short sB[2][512 * 64];   // 2 x 64 KB  (total 160 KB)

    const int bid = blockIdx.x;
    const int xcd = bid & 7;
    const int e = xcd >> 1;
    const int tile = ((bid >> 3) << 1) + (xcd & 1);
    const int n = cnt[e];
    const int base = tile * 128;
    if (base >= n) return;
    const int mcount = min(128, n - base);

    const int tid = threadIdx.x;
    const int lane = tid & 63;
    const int wave = tid >> 6;        // 0..15
    const int lanelo = lane & 15;
    const int g = lane >> 4;          // 0..3
    const int mw = wave >> 3;         // 0..1
    const int nw = wave & 7;          // 0..7

    // ---- A staging map: thread -> (arow, aseg) ----
    const int arow = tid >> 3;        // 0..127
    const int aseg = tid & 7;         // 0..7
    const int atok = perm[e * NTOK + base + min(arow, mcount - 1)];
    const float* axp = x + (size_t)atok * 512 + aseg * 8;
    const float* atp = tws + (size_t)atok * 8;
    const float aw = wgt[atok];
    const int adst = arow * 128 + ((aseg ^ (arow & 7)) << 4);   // bytes

    // ---- B staging: 4 gld groups per wave, pre-swizzled source ----
    const unsigned short* wcE = Wcat + (size_t)e * 512 * KEXT;
    const unsigned short* bsrc[4];
    int bdst[4];
#pragma unroll
    for (int i = 0; i < 4; ++i) {
        const int gi = i * 16 + wave;             // 0..63 row-groups of 8
        const int wr = gi * 8 + (lane >> 3);      // weight row (= out col)
        const int G = (lane & 7) ^ (wr & 7);      // swizzled source granule
        bsrc[i] = wcE + (size_t)wr * KEXT + G * 8;
        bdst[i] = gi * 1024;                      // linear LDS dest, bytes
    }

    f32x4 p0, p1;   // persistent staging pair (x pair reused for odd chunks)
    auto loadA = [&](int ch) {
        if (ch == 16)      { p0 = *(const f32x4*)atp; p1 = *(const f32x4*)(atp + 4); }
        else if (!(ch & 1)) {
            p0 = *(const f32x4*)(axp + (ch >> 1) * 64);
            p1 = *(const f32x4*)(axp + (ch >> 1) * 64 + 4);
        }
    };
    auto writeA = [&](int ch, int buf) {
        s16x8 hv;
        if (ch == 16) {
#pragma unroll
            for (int j = 0; j < 8; ++j) hv[j] = 0;
            if (aseg == 0) {
#pragma unroll
                for (int j = 0; j < 4; ++j) { hv[j] = (short)f2b(p0[j]); hv[j + 4] = (short)f2b(p1[j]); }
            } else if (aseg == 1) {
                hv[0] = (short)f2b(1.0f);
                hv[1] = (short)f2b(aw);
            }
        } else {
            const float s = (ch & 1) ? aw : 1.0f;
#pragma unroll
            for (int j = 0; j < 4; ++j) { hv[j] = (short)f2b(s * p0[j]); hv[j + 4] = (short)f2b(s * p1[j]); }
        }
        *(s16x8*)((char*)sA[buf] + adst) = hv;
    };
    auto issueB = [&](int ch, int buf) {
#pragma unroll
        for (int i = 0; i < 4; ++i)
            gld_lds16(bsrc[i] + ch * 64, (char*)sB[buf] + bdst[i]);
    };

    // ---- prologue: stage chunk 0 (A loads first: B0 stays behind A in FIFO)
    loadA(0);
    issueB(0, 0);
    writeA(0, 0);      // compiler waits A-pair only (4 newer B ops -> vmcnt(4))
    asm volatile("s_waitcnt lgkmcnt(0)" ::: "memory");
    __builtin_amdgcn_sched_barrier(0);

    f32x4 acc[4][4];
#pragma unroll
    for (int mb = 0; mb < 4; ++mb)
#pragma unroll
        for (int nb = 0; nb < 4; ++nb) acc[mb][nb] = (f32x4){0.f, 0.f, 0.f, 0.f};

    for (int c = 0; c < 16; ++c) {
        const int cur = c & 1, nxt = cur ^ 1;
        loadA(c + 1);        // 2 global loads iff c odd (A before B: FIFO order)
        issueB(c + 1, nxt);  // 4 gld_lds into other buffer, stay in flight
        // retire ONLY chunk-c's 4 gld_lds (issued one iteration ago):
        if (c & 1) asm volatile("s_waitcnt vmcnt(6)" ::: "memory");
        else       asm volatile("s_waitcnt vmcnt(4)" ::: "memory");
        __builtin_amdgcn_sched_barrier(0);
        __builtin_amdgcn_s_barrier();     // all waves' chunk-c B landed
        {
            const char* bufA = (const char*)sA[cur];
            const char* bufB = (const char*)sB[cur];
#pragma unroll
            for (int kk = 0; kk < 2; ++kk) {
                s16x8 a[4];
#pragma unroll
                for (int mb = 0; mb < 4; ++mb) {
                    const int row = mw * 64 + mb * 16 + lanelo;
                    a[mb] = *(const s16x8*)(bufA + row * 128 + ((((kk << 2) + g) ^ (row & 7)) << 4));
                }
#pragma unroll
                for (int nb = 0; nb < 4; ++nb) {
                    const int wr = nw * 64 + nb * 16 + lanelo;
                    const s16x8 b = *(const s16x8*)(bufB + wr * 128 + ((((kk << 2) + g) ^ (wr & 7)) << 4));
                    __builtin_amdgcn_s_setprio(1);
#pragma unroll
                    for (int mb = 0; mb < 4; ++mb)
                        acc[mb][nb] = __builtin_amdgcn_mfma_f32_16x16x32_bf16(a[mb], b, acc[mb][nb], 0, 0, 0);
                    __builtin_amdgcn_s_setprio(0);
                }
            }
        }
        writeA(c + 1, nxt);               // compiler-counted wait on A pair
        asm volatile("s_waitcnt lgkmcnt(0)" ::: "memory");
        __builtin_amdgcn_sched_barrier(0);
        __builtin_amdgcn_s_barrier();     // cur free for next iter's issueB
    }

    // ---- tail chunk 16 (buffer 0): one-time full drain is fine here ----
    asm volatile("s_waitcnt vmcnt(0)" ::: "memory");
    __builtin_amdgcn_sched_barrier(0);
    __builtin_amdgcn_s_barrier();
    {
        const char* bufA = (const char*)sA[0];
        const char* bufB = (const char*)sB[0];
#pragma unroll
        for (int kk = 0; kk < 2; ++kk) {
            s16x8 a[4];
#pragma unroll
            for (int mb = 0; mb < 4; ++mb) {
                const int row = mw * 64 + mb * 16 + lanelo;
                a[mb] = *(const s16x8*)(bufA + row * 128 + ((((kk << 2) + g) ^ (row & 7)) << 4));
            }
#pragma unroll
            for (int nb = 0; nb < 4; ++nb) {
                const int wr = nw * 64 + nb * 16 + lanelo;
                const s16x8 b = *(const s16x8*)(bufB + wr * 128 + ((((kk << 2) + g) ^ (wr & 7)) << 4));
                __builtin_amdgcn_s_setprio(1);
#pragma unroll
                for (int mb = 0; mb < 4; ++mb)
                    acc[mb][nb] = __builtin_amdgcn_mfma_f32_16x16x32_bf16(a[mb], b, acc[mb][nb], 0, 0, 0);
                __builtin_amdgcn_s_setprio(0);
            }
        }
    }

    // ---- epilogue: bare scattered store ----
    const int col0 = nw * 64 + lanelo;
#pragma unroll
    for (int mb = 0; mb < 4; ++mb) {
#pragma unroll
        for (int r = 0; r < 4; ++r) {
            const int trow = mw * 64 + mb * 16 + g * 4 + r;
            if (trow < mcount) {
                const int tok = perm[e * NTOK + base + trow];
                float* orow = out + (size_t)tok * 512 + col0;
                orow[0]  = acc[mb][0][r];
                orow[16] = acc[mb][1][r];
                orow[32] = acc[mb][2][r];
                orow[48] = acc[mb][3][r];
            }
        }
    }
}

extern "C" void kernel_launch(void* const* d_in, const int* in_sizes, int n_in,
                              void* d_out, int out_size, void* d_ws, size_t ws_size,
                              hipStream_t stream)
{
    const float* x   = (const float*)d_in[0];
    const float* Wb  = (const float*)d_in[1];
    const float* bb  = (const float*)d_in[2];
    const float* A   = (const float*)d_in[3];
    const float* B   = (const float*)d_in[4];
    const float* ia3 = (const float*)d_in[5];
    const float* Wr  = (const float*)d_in[6];
    const float* br  = (const float*)d_in[7];
    const float* We  = (const float*)d_in[8];
    const float* be  = (const float*)d_in[9];
    float* out = (float*)d_out;

    char* w = (char*)d_ws;
    int* cnt             = (int*)w;                      // 256 B
    unsigned short* Wcat = (unsigned short*)(w + 256);   // 4*512*1088*2 = 4456448
    float* wgt           = (float*)(w + 4456704);        // 65536*4
    float* tws           = (float*)(w + 4718848);        // 65536*8*4
    int* perm            = (int*)(w + 6816000);          // 4*65536*4 -> end 7864576

    hipLaunchKernelGGL(prep_kernel, dim3(8704), dim3(256), 0, stream,
                       Wb, bb, B, ia3, We, be, Wcat, cnt);
    hipLaunchKernelGGL(router_kernel, dim3(1024), dim3(256), 0, stream,
                       x, A, Wr, br, wgt, tws, perm, cnt);
    hipLaunchKernelGGL(main_kernel, dim3(2048), dim3(1024), 0, stream,
                       x, Wcat, wgt, tws, perm, cnt, out);
}